// Round 9
// baseline (147.241 us; speedup 1.0000x reference)
//
#include <hip/hip_runtime.h>

#define N_NODES  50000
#define N_EDGES  600000
#define CHANNELS 128
#define HEADS    8
#define HEAD_DIM 16   // CHANNELS / HEADS
#define CAP      64   // bucket capacity; degrees ~ Poisson(12), P(deg>64) ~ 0
#define CSTRIDE  16   // one cursor per 64B line

#define PREP_BLOCK 256
#define EPT        8                                   // edges per thread (scatter)
#define SCAT_TH    (N_EDGES / EPT)                     // 75000 scatter threads
#define SCAT_VB    ((SCAT_TH + PREP_BLOCK - 1) / PREP_BLOCK)          // 293
#define LOGIT_VB   ((N_NODES * (CHANNELS / 4)) / PREP_BLOCK)          // 6250
#define WPB        4    // waves (nodes) per block in the fused kernel

// ---------------------------------------------------------------------------
// K1 (fused prep):
//  blocks [0, SCAT_VB): scatter src ids (ushort) into per-dst buckets.
//    Phase-split: 8 edge loads -> 8 back-to-back returning atomics (512
//    atomic ops in flight per wave) -> 8 guarded stores.  Max atomic MLP.
//  blocks [SCAT_VB, ...): per-node logit halves + bf16(x), float4/thread.
// ---------------------------------------------------------------------------
__global__ void prep_kernel(const float* __restrict__ x,
                            const float* __restrict__ att,
                            const int*   __restrict__ src,
                            const int*   __restrict__ dst,
                            int*            __restrict__ cursor,
                            unsigned short* __restrict__ bucket,
                            float*          __restrict__ ls8,
                            float*          __restrict__ ld8,
                            unsigned short* __restrict__ xb) {
    int b = blockIdx.x;
    if (b < SCAT_VB) {
        int t = b * PREP_BLOCK + threadIdx.x;
        if (t < SCAT_TH) {
            int dd[EPT], ss[EPT], pp[EPT];
#pragma unroll
            for (int k = 0; k < EPT; ++k) {
                int e = t + k * SCAT_TH;            // coalesced per k
                dd[k] = dst[e];
                ss[k] = src[e];
            }
#pragma unroll
            for (int k = 0; k < EPT; ++k)
                pp[k] = atomicAdd(&cursor[dd[k] * CSTRIDE], 1);
#pragma unroll
            for (int k = 0; k < EPT; ++k)
                if (pp[k] < CAP)
                    bucket[(size_t)dd[k] * CAP + pp[k]] = (unsigned short)ss[k];
        }
    } else {
        int gid = (b - SCAT_VB) * PREP_BLOCK + threadIdx.x;  // (node, float4-slot)
        int n  = gid >> 5;          // 32 float4s per node
        int c4 = gid & 31;
        int h  = c4 >> 2;           // 4 float4s per head
        int j4 = c4 & 3;

        float4 v = ((const float4*)x)[gid];

        // bf16 round-to-nearest-even, packed store (8B)
        unsigned int ux = __float_as_uint(v.x), uy = __float_as_uint(v.y);
        unsigned int uz = __float_as_uint(v.z), uw = __float_as_uint(v.w);
        ushort4 pk;
        pk.x = (unsigned short)((ux + 0x7FFFu + ((ux >> 16) & 1u)) >> 16);
        pk.y = (unsigned short)((uy + 0x7FFFu + ((uy >> 16) & 1u)) >> 16);
        pk.z = (unsigned short)((uz + 0x7FFFu + ((uz >> 16) & 1u)) >> 16);
        pk.w = (unsigned short)((uw + 0x7FFFu + ((uw >> 16) & 1u)) >> 16);
        ((ushort4*)xb)[gid] = pk;

        // att row = 32 floats = 8 float4s: [a_src(4), a_dst(4)]
        float4 as4 = ((const float4*)att)[h * 8 + j4];
        float4 ad4 = ((const float4*)att)[h * 8 + 4 + j4];
        float ts = v.x * as4.x + v.y * as4.y + v.z * as4.z + v.w * as4.w;
        float td = v.x * ad4.x + v.y * ad4.y + v.z * ad4.z + v.w * ad4.w;
        ts += __shfl_xor(ts, 1, 4); ts += __shfl_xor(ts, 2, 4);
        td += __shfl_xor(td, 1, 4); td += __shfl_xor(td, 2, 4);
        if (j4 == 0) {
            ls8[n * HEADS + h] = ts;
            ld8[n * HEADS + h] = td;
        }
    }
}

// ---------------------------------------------------------------------------
// K2: fused GAT aggregation.  One 64-lane wave per node.
// Pass 1 (layout h=lane>>3, j=lane&7): logits in registers, 8-lane shuffle
//   max (clamped at 0 == reference's max(seg_max,0)), one exp per (edge,head)
//   -> LDS, denominator reduced in-register.
// Pass 2 (layout r=lane>>5, l32=lane&31): TWO edges per wave-load — lane
//   loads ushort4 (8B) so each half-wave covers one full 256B bf16 row.
//   Window of 8 slots = 16 edges in flight; one ds_read(p) + 8 unpack ops +
//   4 FMA per edge-pair per lane.  Even/odd-edge accumulators merged by
//   __shfl_xor(...,32); half-wave float4 store (512B/node).
// ---------------------------------------------------------------------------
__global__ void fused_gat_kernel(const unsigned short* __restrict__ xb,
                                 const float* __restrict__ ls8,
                                 const float* __restrict__ ld8,
                                 const int*   __restrict__ cursor,
                                 const unsigned short* __restrict__ bucket,
                                 float*       __restrict__ out) {
    __shared__ float s_p[WPB * CAP * HEADS];     // 8 KB: staged softmax numerators

    int wave = threadIdx.x >> 6;                 // 0..WPB-1
    int lane = threadIdx.x & 63;
    int n = blockIdx.x * WPB + wave;
    if (n >= N_NODES) return;
    int h = lane >> 3;                           // pass-1 head
    int j = lane & 7;
    int r   = lane >> 5;                         // pass-2: which edge of pair
    int l32 = lane & 31;                         // pass-2: channel quad
    int h2  = l32 >> 2;                          // pass-2 head

    int   cnt_raw = cursor[n * CSTRIDE];
    int   myidx   = (int)bucket[(size_t)n * CAP + lane];
    float ldst    = ld8[n * HEADS + h];
    int cnt = (cnt_raw > CAP) ? CAP : cnt_raw;

    float* sp = s_p + wave * (CAP * HEADS);

    // ---- pass 1: logits in registers, per-head max, single exp per value ----
    float av[8];
    float mymax = -1e30f;
#pragma unroll
    for (int k = 0; k < 8; ++k) {
        int i = j + 8 * k;
        av[k] = -1e30f;
        if (i < cnt) {
            int   s  = __shfl(myidx, i);
            float lg = ls8[s * HEADS + h] + ldst;
            float a  = (lg >= 0.0f) ? lg : 0.2f * lg;   // LeakyReLU(0.2)
            av[k] = a;
            mymax = fmaxf(mymax, a);
        }
    }
#pragma unroll
    for (int o = 4; o >= 1; o >>= 1) mymax = fmaxf(mymax, __shfl_xor(mymax, o, 8));
    float m = fmaxf(mymax, 0.0f);                // reference clamps seg_max at 0

    float myl = 0.0f;
#pragma unroll
    for (int k = 0; k < 8; ++k) {
        int i = j + 8 * k;
        if (i < cnt) {
            float p = __expf(av[k] - m);
            sp[i * HEADS + h] = p;               // 2-way bank aliasing only
            myl += p;
        }
    }
#pragma unroll
    for (int o = 4; o >= 1; o >>= 1) myl += __shfl_xor(myl, o, 8);

    // ---- pass 2: weighted accumulate, 2 edges/load, window 8 slots ----
    // slot k covers edges (2k, 2k+1); this lane handles edge 2k+r.
#define LP(k) ( ((const uint2*)(xb + (size_t)__shfl(myidx, ((2*(k)+r) < cnt) ? (2*(k)+r) : 0) * CHANNELS))[l32] )
    uint2 q[8];
#pragma unroll
    for (int k = 0; k < 8; ++k) q[k] = LP(k);

    float a0 = 0.f, a1 = 0.f, a2 = 0.f, a3 = 0.f;
    int npair = (cnt + 1) >> 1;
    int k = 0;
    for (; k + 4 <= npair; k += 4) {
#pragma unroll
        for (int u = 0; u < 4; ++u) {
            int e2 = 2 * (k + u) + r;
            float p = (e2 < cnt) ? sp[e2 * HEADS + h2] : 0.0f;
            uint2 qq = q[u];
            a0 += p * __uint_as_float(qq.x << 16);
            a1 += p * __uint_as_float(qq.x & 0xFFFF0000u);
            a2 += p * __uint_as_float(qq.y << 16);
            a3 += p * __uint_as_float(qq.y & 0xFFFF0000u);
        }
#pragma unroll
        for (int u = 0; u < 4; ++u) q[u] = q[u + 4];
#pragma unroll
        for (int u = 0; u < 4; ++u) q[u + 4] = LP(k + 8 + u);
    }
    for (; k < npair; ++k) {                     // tail 0..3 pairs
        int e2 = 2 * k + r;
        float p = (e2 < cnt) ? sp[e2 * HEADS + h2] : 0.0f;
        uint2 qq = q[0];
        a0 += p * __uint_as_float(qq.x << 16);
        a1 += p * __uint_as_float(qq.x & 0xFFFF0000u);
        a2 += p * __uint_as_float(qq.y << 16);
        a3 += p * __uint_as_float(qq.y & 0xFFFF0000u);
#pragma unroll
        for (int u = 0; u < 7; ++u) q[u] = q[u + 1];
    }
#undef LP

    // merge even/odd-edge halves
    a0 += __shfl_xor(a0, 32);
    a1 += __shfl_xor(a1, 32);
    a2 += __shfl_xor(a2, 32);
    a3 += __shfl_xor(a3, 32);

    // denominator for pass-2 head layout: lane h2*8 holds head h2's sum
    float denom = __shfl(myl, h2 * 8);
    float inv = 1.0f / fmaxf(denom, 1e-10f);

    if (lane < 32) {
        float4 o4 = make_float4(a0 * inv, a1 * inv, a2 * inv, a3 * inv);
        ((float4*)(out + (size_t)n * CHANNELS))[l32] = o4;
    }
}

// ---------------------------------------------------------------------------
extern "C" void kernel_launch(void* const* d_in, const int* in_sizes, int n_in,
                              void* d_out, int out_size, void* d_ws, size_t ws_size,
                              hipStream_t stream) {
    const float* x   = (const float*)d_in[0];
    const int*   ei  = (const int*)  d_in[1];   // (2, N_EDGES) row-major
    const float* att = (const float*)d_in[2];
    const int* src = ei;
    const int* dst = ei + N_EDGES;
    float* out = (float*)d_out;

    // Workspace layout:
    //   cursor : N_NODES * CSTRIDE ints      (3.2 MB)
    //   bucket : N_NODES * CAP ushorts       (6.4 MB)
    //   ls8    : N_NODES * HEADS floats      (1.6 MB)
    //   ld8    : N_NODES * HEADS floats      (1.6 MB)
    //   xb     : N_NODES * CHANNELS ushorts  (12.8 MB)
    int*            cursor = (int*)d_ws;
    unsigned short* bucket = (unsigned short*)(cursor + (size_t)N_NODES * CSTRIDE);
    float*          ls8    = (float*)(bucket + (size_t)N_NODES * CAP);
    float*          ld8    = ls8 + (size_t)N_NODES * HEADS;
    unsigned short* xb     = (unsigned short*)(ld8 + (size_t)N_NODES * HEADS);

    hipMemsetAsync(cursor, 0, sizeof(int) * (size_t)N_NODES * CSTRIDE, stream);

    prep_kernel<<<SCAT_VB + LOGIT_VB, PREP_BLOCK, 0, stream>>>(
        x, att, src, dst, cursor, bucket, ls8, ld8, xb);

    {
        int grid = (N_NODES + WPB - 1) / WPB;
        fused_gat_kernel<<<grid, 64 * WPB, 0, stream>>>(
            xb, ls8, ld8, cursor, bucket, out);
    }
}